// Round 4
// baseline (44.771 us; speedup 1.0000x reference)
//
#include <hip/hip_runtime.h>
#include <math.h>

#define NN 4096
#define DD 7
#define HH 8
#define CUT 3.6f
#define TPB 256
#define JSPLIT 16
#define JCH 256              // j-nodes per chunk
#define NRT 16               // row tiles of 256 rows

// part layout: part[(y*8+ch)*NN + k]  (k coalesced)

// ---------------- K1: in-block MLP for j-chunk + pairwise partials ----------------
__global__ __launch_bounds__(TPB) void k_pair(
    const float* __restrict__ x,
    const float* __restrict__ w1, const float* __restrict__ b1,
    const float* __restrict__ w2, const float* __restrict__ b2,
    const float* __restrict__ w3, const float* __restrict__ b3,
    float* __restrict__ part)
{
    __shared__ float4 tile[JCH * 3];   // 12 KiB
    const int xb = blockIdx.x;         // row tile 0..15
    const int y  = blockIdx.y;         // j chunk 0..15
    const int t  = threadIdx.x;

    // ---- MLP for j-node jg = y*256 + t -> LDS record ----
    {
        const int jg = y * JCH + t;
        float xi[DD];
#pragma unroll
        for (int i = 0; i < DD; ++i) xi[i] = x[jg * DD + i];

        float h1[HH];
#pragma unroll
        for (int o = 0; o < HH; ++o) {
            float a = b1[o];
#pragma unroll
            for (int i = 0; i < DD; ++i) a = fmaf(xi[i], w1[i * HH + o], a);
            h1[o] = atanf(a);
        }
        float h2[HH];
#pragma unroll
        for (int o = 0; o < HH; ++o) {
            float a = b2[o];
#pragma unroll
            for (int i = 0; i < HH; ++i) a = fmaf(h1[i], w2[i * HH + o], a);
            h2[o] = atanf(a);
        }
        float m[23];
#pragma unroll
        for (int c = 0; c < 23; ++c) {
            float a = b3[c];
#pragma unroll
            for (int i = 0; i < HH; ++i) a = fmaf(h2[i], w3[i * 23 + c], a);
            m[c] = a;
        }
        float s = 0.f;
#pragma unroll
        for (int k = 0; k < 8; ++k) s = fmaf(m[15 + k], m[7 + k], s);
        const float e = expf(s);       // global-max cancels in Num/Den; s is O(1)

        tile[t * 3 + 0] = make_float4(xi[0], xi[1], xi[2], e);
        tile[t * 3 + 1] = make_float4(e * m[0], e * m[1], e * m[2], e * m[3]);
        tile[t * 3 + 2] = make_float4(e * m[4], e * m[5], e * m[6], 0.f);
    }
    __syncthreads();

    // ---- pair loop: 1 row/thread, uniform-j LDS broadcast ----
    const int row = xb * TPB + t;
    const float p0 = x[row * DD + 0];
    const float p1 = x[row * DD + 1];
    const float p2 = x[row * DD + 2];

    float acc[8];
#pragma unroll
    for (int ch = 0; ch < 8; ++ch) acc[ch] = 0.f;

#pragma unroll 4
    for (int j = 0; j < JCH; ++j) {
        float4 a = tile[j * 3 + 0];
        float4 b = tile[j * 3 + 1];
        float4 c = tile[j * 3 + 2];
        float dist = fabsf(p0 - a.x) + fabsf(p1 - a.y) + fabsf(p2 - a.z);
        float msel = (dist <= CUT) ? 1.0f : 0.0f;
        acc[0] = fmaf(msel, b.x, acc[0]);
        acc[1] = fmaf(msel, b.y, acc[1]);
        acc[2] = fmaf(msel, b.z, acc[2]);
        acc[3] = fmaf(msel, b.w, acc[3]);
        acc[4] = fmaf(msel, c.x, acc[4]);
        acc[5] = fmaf(msel, c.y, acc[5]);
        acc[6] = fmaf(msel, c.z, acc[6]);
        acc[7] = fmaf(msel, a.w, acc[7]);
    }
#pragma unroll
    for (int ch = 0; ch < 8; ++ch)
        part[(size_t)(y * 8 + ch) * NN + row] = acc[ch];   // coalesced
}

// ---------------- K2: combine partials + prefix + encode/decode ----------------
__global__ __launch_bounds__(TPB) void k_scanfinal(
    const float* __restrict__ x, const float* __restrict__ part,
    const float* __restrict__ we, const float* __restrict__ be,
    const float* __restrict__ wd, const float* __restrict__ bd,
    float* __restrict__ out)
{
    const int b = blockIdx.x;          // row block 0..15
    const int t = threadIdx.x;

    __shared__ float sbase[8];
    __shared__ float wtot[4][8];

    // ---- A1: base[ch] = sum over k < b*256 of T[k][ch], 32 lanes per channel ----
    {
        const int ch = t >> 5, lane = t & 31;
        float bs = 0.f;
        const int n4 = b * 64;         // float4 count of k < b*256
        for (int k4 = lane; k4 < n4; k4 += 32) {
#pragma unroll
            for (int y = 0; y < JSPLIT; ++y) {
                const float4* p4 = (const float4*)(part + (size_t)(y * 8 + ch) * NN);
                float4 v = p4[k4];
                bs += (v.x + v.y) + (v.z + v.w);
            }
        }
#pragma unroll
        for (int off = 16; off > 0; off >>= 1) bs += __shfl_xor(bs, off, 32);
        if (lane == 0) sbase[ch] = bs;
    }

    // ---- A2: T for own row k = b*256 + t ----
    const int k = b * TPB + t;
    float T[8];
#pragma unroll
    for (int ch = 0; ch < 8; ++ch) {
        float v = 0.f;
#pragma unroll
        for (int y = 0; y < JSPLIT; ++y)
            v += part[(size_t)(y * 8 + ch) * NN + k];
        T[ch] = v;
    }

    // ---- A3: inclusive scan across 256 threads per channel ----
    const int lane = t & 63, wv = t >> 6;
    float sc[8];
#pragma unroll
    for (int ch = 0; ch < 8; ++ch) {
        float v = T[ch];
#pragma unroll
        for (int off = 1; off < 64; off <<= 1) {
            float o = __shfl_up(v, off, 64);
            if (lane >= off) v += o;
        }
        if (lane == 63) wtot[wv][ch] = v;
        sc[ch] = v;
    }
    __syncthreads();

    float pref[8];
#pragma unroll
    for (int ch = 0; ch < 8; ++ch) {
        float woff = sbase[ch];
#pragma unroll
        for (int w = 0; w < 4; ++w) if (w < wv) woff += wtot[w][ch];
        pref[ch] = woff + sc[ch];
    }

    // ---- final: agg = Num/Den; encode + decode ----
    float v[14];
#pragma unroll
    for (int i = 0; i < DD; ++i) v[i] = x[k * DD + i];
    const float den = pref[7];
#pragma unroll
    for (int d = 0; d < DD; ++d) v[DD + d] = pref[d] / den;

    float codes[HH];
#pragma unroll
    for (int o = 0; o < HH; ++o) {
        float a = be[o];
#pragma unroll
        for (int i = 0; i < 14; ++i) a = fmaf(v[i], we[i * HH + o], a);
        codes[o] = atanf(a);
    }
#pragma unroll
    for (int d = 0; d < DD; ++d) {
        float a = bd[d];
#pragma unroll
        for (int o = 0; o < HH; ++o) a = fmaf(codes[o], wd[o * DD + d], a);
        out[k * DD + d] = a;
    }
}

extern "C" void kernel_launch(void* const* d_in, const int* in_sizes, int n_in,
                              void* d_out, int out_size, void* d_ws, size_t ws_size,
                              hipStream_t stream)
{
    const float* x  = (const float*)d_in[0];
    const float* w1 = (const float*)d_in[1];
    const float* b1 = (const float*)d_in[2];
    const float* w2 = (const float*)d_in[3];
    const float* b2 = (const float*)d_in[4];
    const float* w3 = (const float*)d_in[5];
    const float* b3 = (const float*)d_in[6];
    const float* we = (const float*)d_in[7];
    const float* be = (const float*)d_in[8];
    const float* wd = (const float*)d_in[9];
    const float* bd = (const float*)d_in[10];
    float* out = (float*)d_out;

    float* part = (float*)d_ws;        // 16*8*4096 floats = 2 MiB

    k_pair     <<<dim3(NRT, JSPLIT), TPB, 0, stream>>>(x, w1, b1, w2, b2, w3, b3, part);
    k_scanfinal<<<NRT, TPB, 0, stream>>>(x, part, we, be, wd, bd, out);
}

// Round 5
// 26.196 us; speedup vs baseline: 1.7091x; 1.7091x over previous
//
#include <hip/hip_runtime.h>
#include <math.h>

#define NN 4096
#define DD 7
#define HH 8
#define CUT 3.6f
#define JSPLIT 16
#define JCH 256              // j-nodes per chunk
#define NRT 16               // row tiles of 256 rows
#define TPB 512

// tile record: 3 float4/node: [p0,p1,p2,e][e*m0..e*m3][e*m4..e*m6,0]
// part layout: part[(y*8+ch)*NN + row]         (row coalesced)
// bsum layout: bsum[xb*128 + y*8 + ch]         (block column-sums)

// ---------------- K1: in-block MLP for j-chunk + pairwise partials ----------------
__global__ __launch_bounds__(TPB) void k_pair(
    const float* __restrict__ x,
    const float* __restrict__ w1, const float* __restrict__ b1,
    const float* __restrict__ w2, const float* __restrict__ b2,
    const float* __restrict__ w3, const float* __restrict__ b3,
    float* __restrict__ part, float* __restrict__ bsum)
{
    __shared__ float4 tile[JCH * 3];   // 12 KiB
    __shared__ float  red1[64][8];     // per-group row sums
    __shared__ float  red2[8][8];
    const int xb = blockIdx.x;         // row tile 0..15
    const int y  = blockIdx.y;         // j chunk 0..15
    const int t  = threadIdx.x;

    // ---- MLP for j-node jg = y*256 + t (t<256) -> LDS record ----
    if (t < JCH) {
        const int jg = y * JCH + t;
        float xi[DD];
#pragma unroll
        for (int i = 0; i < DD; ++i) xi[i] = x[jg * DD + i];

        float h1[HH];
#pragma unroll
        for (int o = 0; o < HH; ++o) {
            float a = b1[o];
#pragma unroll
            for (int i = 0; i < DD; ++i) a = fmaf(xi[i], w1[i * HH + o], a);
            h1[o] = atanf(a);
        }
        float h2[HH];
#pragma unroll
        for (int o = 0; o < HH; ++o) {
            float a = b2[o];
#pragma unroll
            for (int i = 0; i < HH; ++i) a = fmaf(h1[i], w2[i * HH + o], a);
            h2[o] = atanf(a);
        }
        float m[23];
#pragma unroll
        for (int c = 0; c < 23; ++c) {
            float a = b3[c];
#pragma unroll
            for (int i = 0; i < HH; ++i) a = fmaf(h2[i], w3[i * 23 + c], a);
            m[c] = a;
        }
        float s = 0.f;
#pragma unroll
        for (int k = 0; k < 8; ++k) s = fmaf(m[15 + k], m[7 + k], s);
        const float e = expf(s);       // global max cancels in Num/Den (validated R4)

        tile[t * 3 + 0] = make_float4(xi[0], xi[1], xi[2], e);
        tile[t * 3 + 1] = make_float4(e * m[0], e * m[1], e * m[2], e * m[3]);
        tile[t * 3 + 2] = make_float4(e * m[4], e * m[5], e * m[6], 0.f);
    }
    __syncthreads();

    // ---- pair loop: 8 j-lanes x 4 rows/thread ----
    const int jl   = t & 7;            // j lane 0..7
    const int grp  = t >> 3;           // row group 0..63
    const int row0 = xb * 256 + grp * 4;

    float px[4][3];
#pragma unroll
    for (int rr = 0; rr < 4; ++rr) {
        px[rr][0] = x[(row0 + rr) * DD + 0];
        px[rr][1] = x[(row0 + rr) * DD + 1];
        px[rr][2] = x[(row0 + rr) * DD + 2];
    }

    float acc[4][8];
#pragma unroll
    for (int rr = 0; rr < 4; ++rr)
#pragma unroll
        for (int ch = 0; ch < 8; ++ch) acc[rr][ch] = 0.f;

#pragma unroll 4
    for (int k = 0; k < JCH / 8; ++k) {      // 32 iters
        const int jj = k * 8 + jl;
        float4 a = tile[jj * 3 + 0];
        float4 b = tile[jj * 3 + 1];
        float4 c = tile[jj * 3 + 2];
#pragma unroll
        for (int rr = 0; rr < 4; ++rr) {
            float dist = fabsf(px[rr][0] - a.x) + fabsf(px[rr][1] - a.y)
                       + fabsf(px[rr][2] - a.z);
            float msel = (dist <= CUT) ? 1.0f : 0.0f;
            acc[rr][0] = fmaf(msel, b.x, acc[rr][0]);
            acc[rr][1] = fmaf(msel, b.y, acc[rr][1]);
            acc[rr][2] = fmaf(msel, b.z, acc[rr][2]);
            acc[rr][3] = fmaf(msel, b.w, acc[rr][3]);
            acc[rr][4] = fmaf(msel, c.x, acc[rr][4]);
            acc[rr][5] = fmaf(msel, c.y, acc[rr][5]);
            acc[rr][6] = fmaf(msel, c.z, acc[rr][6]);
            acc[rr][7] = fmaf(msel, a.w, acc[rr][7]);
        }
    }

    // reduce across the 8 j-lanes
#pragma unroll
    for (int rr = 0; rr < 4; ++rr)
#pragma unroll
        for (int ch = 0; ch < 8; ++ch) {
            float v = acc[rr][ch];
            v += __shfl_xor(v, 4, 8);
            v += __shfl_xor(v, 2, 8);
            v += __shfl_xor(v, 1, 8);
            acc[rr][ch] = v;
        }

    if (jl == 0) {
#pragma unroll
        for (int ch = 0; ch < 8; ++ch) {
            float4* pp = (float4*)(part + (size_t)(y * 8 + ch) * NN + row0);
            *pp = make_float4(acc[0][ch], acc[1][ch], acc[2][ch], acc[3][ch]);
            red1[grp][ch] = ((acc[0][ch] + acc[1][ch]) + (acc[2][ch] + acc[3][ch]));
        }
    }
    __syncthreads();
    if (t < 64) {                       // 8 segs x 8 ch
        const int ch = t & 7, seg = t >> 3;
        float s = 0.f;
#pragma unroll
        for (int g = 0; g < 8; ++g) s += red1[seg * 8 + g][ch];
        red2[seg][ch] = s;
    }
    __syncthreads();
    if (t < 8) {
        float s = 0.f;
#pragma unroll
        for (int seg = 0; seg < 8; ++seg) s += red2[seg][t];
        bsum[xb * 128 + y * 8 + t] = s;
    }
}

// ---------------- K2: combine partials + prefix + encode/decode ----------------
__global__ __launch_bounds__(256) void k_scanfinal(
    const float* __restrict__ x, const float* __restrict__ part,
    const float* __restrict__ bsum,
    const float* __restrict__ we, const float* __restrict__ be,
    const float* __restrict__ wd, const float* __restrict__ bd,
    float* __restrict__ out)
{
    const int b = blockIdx.x;          // row block 0..15
    const int t = threadIdx.x;

    __shared__ float red[256];
    __shared__ float basech[8];
    __shared__ float wtot[4][8];

    // ---- base[ch] from per-block column sums of row tiles xb < b ----
    {
        float p = 0.f;
        for (int i = t; i < b * 128; i += 256) p += bsum[i];   // i&7 == t&7
        red[t] = p;
    }
    __syncthreads();
    if (t < 8) {
        float s = 0.f;
#pragma unroll
        for (int q = 0; q < 32; ++q) s += red[t + 8 * q];
        basech[t] = s;
    }

    // ---- T for own row k = b*256 + t ----
    const int k = b * 256 + t;
    float T[8];
#pragma unroll
    for (int ch = 0; ch < 8; ++ch) {
        float v = 0.f;
#pragma unroll
        for (int y = 0; y < JSPLIT; ++y)
            v += part[(size_t)(y * 8 + ch) * NN + k];
        T[ch] = v;
    }

    // ---- inclusive scan across 256 threads per channel ----
    const int lane = t & 63, wv = t >> 6;
    float sc[8];
#pragma unroll
    for (int ch = 0; ch < 8; ++ch) {
        float v = T[ch];
#pragma unroll
        for (int off = 1; off < 64; off <<= 1) {
            float o = __shfl_up(v, off, 64);
            if (lane >= off) v += o;
        }
        if (lane == 63) wtot[wv][ch] = v;
        sc[ch] = v;
    }
    __syncthreads();

    float pref[8];
#pragma unroll
    for (int ch = 0; ch < 8; ++ch) {
        float woff = basech[ch];
#pragma unroll
        for (int w = 0; w < 4; ++w) if (w < wv) woff += wtot[w][ch];
        pref[ch] = woff + sc[ch];
    }

    // ---- final: agg = Num/Den; encode + decode ----
    float v[14];
#pragma unroll
    for (int i = 0; i < DD; ++i) v[i] = x[k * DD + i];
    const float den = pref[7];
#pragma unroll
    for (int d = 0; d < DD; ++d) v[DD + d] = pref[d] / den;

    float codes[HH];
#pragma unroll
    for (int o = 0; o < HH; ++o) {
        float a = be[o];
#pragma unroll
        for (int i = 0; i < 14; ++i) a = fmaf(v[i], we[i * HH + o], a);
        codes[o] = atanf(a);
    }
#pragma unroll
    for (int d = 0; d < DD; ++d) {
        float a = bd[d];
#pragma unroll
        for (int o = 0; o < HH; ++o) a = fmaf(codes[o], wd[o * DD + d], a);
        out[k * DD + d] = a;
    }
}

extern "C" void kernel_launch(void* const* d_in, const int* in_sizes, int n_in,
                              void* d_out, int out_size, void* d_ws, size_t ws_size,
                              hipStream_t stream)
{
    const float* x  = (const float*)d_in[0];
    const float* w1 = (const float*)d_in[1];
    const float* b1 = (const float*)d_in[2];
    const float* w2 = (const float*)d_in[3];
    const float* b2 = (const float*)d_in[4];
    const float* w3 = (const float*)d_in[5];
    const float* b3 = (const float*)d_in[6];
    const float* we = (const float*)d_in[7];
    const float* be = (const float*)d_in[8];
    const float* wd = (const float*)d_in[9];
    const float* bd = (const float*)d_in[10];
    float* out = (float*)d_out;

    float* part = (float*)d_ws;                 // 16*8*4096 floats = 2 MiB
    float* bsum = part + (size_t)JSPLIT * 8 * NN;  // 16*16*8 = 2048 floats

    k_pair     <<<dim3(NRT, JSPLIT), TPB, 0, stream>>>(x, w1, b1, w2, b2, w3, b3,
                                                       part, bsum);
    k_scanfinal<<<NRT, 256, 0, stream>>>(x, part, bsum, we, be, wd, bd, out);
}